// Round 5
// baseline (429.631 us; speedup 1.0000x reference)
//
#include <hip/hip_runtime.h>
#include <stdint.h>

// Problem constants: B=8, S=2048, IN=4096, OUT=64, L=16
#define NB   8
#define NS   2048
#define NIN  4096
#define NOUT 64
#define NL   16

constexpr int MT    = 16;          // m rows per block
constexpr int KT    = 128;         // k floats per LDS tile
constexpr int KHALF = NIN / 2;     // 2048 k per block (2-way k-split over blocks)
constexpr int NT    = KHALF / KT;  // 16 tiles

typedef __attribute__((ext_vector_type(8))) short  s16x8;   // MFMA A/B frag (8 bf16)
typedef __attribute__((ext_vector_type(4))) float  f32x4;   // MFMA acc
typedef __attribute__((ext_vector_type(4))) float  fv4;
typedef __attribute__((ext_vector_type(4))) __bf16 bf16x4;

// 8 fp32 -> 8 bf16 RNE via v_cvt_pk_bf16_f32 (1 inst / 2 elems).
__device__ __forceinline__ s16x8 cvt8(float4 a, float4 b) {
    fv4 va = {a.x, a.y, a.z, a.w};
    fv4 vb = {b.x, b.y, b.z, b.w};
    union { struct { bf16x4 lo, hi; } h; s16x8 s; } u;
    u.h.lo = __builtin_convertvector(va, bf16x4);
    u.h.hi = __builtin_convertvector(vb, bf16x4);
    return u.s;
}

// Multi-LoRA linear, round-3 proven structure + block-level 2-way K-split.
// Grid: 2048 = 8 batches (XCD-affine via bx&7) x 128 m-tiles x 2 k-halves.
// Block: 256 threads = 4 waves; wave wv owns out cols [wv*16, wv*16+16).
// x staged fp32->bf16 into XOR-swizzled double-buffered LDS (one barrier per
// K=128 tile; drain overlapped by ~5 resident blocks/CU). Weight read as
// fp32 straight from global (no workspace, no convert dispatch); raw B
// prefetched one tile ahead, converted at tile END (the barrier drains
// vmcnt(0) anyway, so the cvt wait is free).
// Partials combined with unsafeAtomicAdd onto memset-zeroed out
// (exactly 2 commutative fp32 adds per output -> deterministic).
//   A-frag: x[m = lane&15][k = (lane>>4)*8 + j]  (bf16, LDS)
//   B-frag: w[n = lane&15 + wv*16][same k]       (fp32 global -> cvt)
//   D:      col = lane&15 (n), row = (lane>>4)*4 + reg (m)   [verified r1]
__global__ __launch_bounds__(256, 5) void mll_kernel(const float* __restrict__ x,
                                                     const int* __restrict__ ids,
                                                     const float* __restrict__ w,
                                                     float* __restrict__ out) {
    // [2 buf][16 rows][128 bf16], 16B chunks XOR-swizzled by row
    __shared__ __align__(16) unsigned short xs[2 * MT * KT];  // 8 KB

    const int bx   = blockIdx.x;
    const int b    = bx & 7;           // batch; bx%8 ~ XCD id -> adapter L2-affine
    const int mt   = (bx >> 3) & 127;  // m-tile
    const int kh   = bx >> 10;         // k-half 0..1
    const int aid  = ids[b];
    const int t    = threadIdx.x;
    const int lane = t & 63;
    const int wv   = t >> 6;
    const int l15  = lane & 15;
    const int lk   = lane >> 4;        // 0..3
    const int koff = kh * KHALF;

    // ---- staging coords: thread t loads row t>>4, 8-float chunk q = t&15
    const int srow = t >> 4;           // 0..15
    const int sq   = t & 15;           // 0..15
    const float* gsrc = x + ((size_t)(b * NS + mt * MT + srow)) * NIN + koff + sq * 8;
    const int woff = srow * KT + ((sq ^ srow) * 8);   // swizzled LDS elem offset

    // ---- A-frag LDS read offsets (per K=32 step s: chunk q = s*4+lk)
    int roff[4];
#pragma unroll
    for (int s = 0; s < 4; ++s) roff[s] = l15 * KT + (((s * 4 + lk) ^ l15) * 8);

    // ---- B pointer (fp32, per-wave private n-rows)
    const float* wb = w + ((size_t)(aid * NOUT + wv * 16 + l15)) * NIN + koff + lk * 8;

    f32x4 acc = {0.f, 0.f, 0.f, 0.f};

    // ---- prologue: x tile0 -> LDS buf0; x tile1 -> regs; B tile0 raw -> cvt
    {
        const float4* g0 = (const float4*)gsrc;
        *(s16x8*)(xs + woff) = cvt8(g0[0], g0[1]);
    }
    const float4* g1 = (const float4*)(gsrc + KT);
    float4 r0 = g1[0], r1 = g1[1];

    float4 braw[8];
#pragma unroll
    for (int s = 0; s < 4; ++s) {
        const float4* wp = (const float4*)(wb + s * 32);
        braw[2 * s] = wp[0]; braw[2 * s + 1] = wp[1];
    }
    s16x8 bcur[4];
#pragma unroll
    for (int s = 0; s < 4; ++s) bcur[s] = cvt8(braw[2 * s], braw[2 * s + 1]);
    __syncthreads();

    for (int tile = 0; tile < NT; ++tile) {
        const int p = tile & 1;

        // x prefetch tile+2 (clamped; tail reload harmless)
        const int pt = (tile + 2 < NT) ? (tile + 2) : (NT - 1);
        const float4* gn = (const float4*)(gsrc + (size_t)pt * KT);
        float4 n0 = gn[0], n1 = gn[1];

        // B raw prefetch tile+1 (clamped)
        const int bt = (tile + 1 < NT) ? (tile + 1) : (NT - 1);
#pragma unroll
        for (int s = 0; s < 4; ++s) {
            const float4* wp = (const float4*)(wb + (size_t)bt * KT + s * 32);
            braw[2 * s] = wp[0]; braw[2 * s + 1] = wp[1];
        }

        // compute tile from LDS buf p (4 K=32 MFMA steps)
        const unsigned short* buf = xs + p * (MT * KT);
#pragma unroll
        for (int s = 0; s < 4; ++s) {
            s16x8 af = *(const s16x8*)(buf + roff[s]);
            acc = __builtin_amdgcn_mfma_f32_16x16x32_bf16(af, bcur[s], acc, 0, 0, 0);
        }

        // stage x tile+1 (in r0/r1) into the other buffer
        if (tile + 1 < NT) {
            *(s16x8*)(xs + (1 - p) * (MT * KT) + woff) = cvt8(r0, r1);
        }
        r0 = n0; r1 = n1;

        // convert raw B for next tile (vmcnt drained by the barrier anyway)
#pragma unroll
        for (int s = 0; s < 4; ++s) bcur[s] = cvt8(braw[2 * s], braw[2 * s + 1]);
        __syncthreads();
    }

    // ---- epilogue: accumulate k-half partial into out
    // D col = lane&15 (n), row = (lane>>4)*4 + reg (m); 2 adds/output total.
    float* ob = out + ((size_t)(b * NS + mt * MT)) * NOUT + wv * 16 + l15;
#pragma unroll
    for (int r = 0; r < 4; ++r) {
        unsafeAtomicAdd(&ob[(size_t)(lk * 4 + r) * NOUT], acc[r]);
    }
}

extern "C" void kernel_launch(void* const* d_in, const int* in_sizes, int n_in,
                              void* d_out, int out_size, void* d_ws, size_t ws_size,
                              hipStream_t stream) {
    const float* x   = (const float*)d_in[0];
    const int*   ids = (const int*)d_in[1];
    const float* w   = (const float*)d_in[2];
    float*       out = (float*)d_out;

    // zero out (atomic accumulation target); memset node is graph-capture legal
    hipMemsetAsync(d_out, 0, (size_t)out_size * sizeof(float), stream);

    const int grid = NB * (NS / MT) * 2;  // 2048 (x2 k-split)
    mll_kernel<<<grid, 256, 0, stream>>>(x, ids, w, out);
}